// Round 2
// baseline (108.236 us; speedup 1.0000x reference)
//
#include <hip/hip_runtime.h>
#include <hip/hip_bf16.h>

#define TEMP_INV 14.285714285714286f   // 1/0.07
#define NBATCH 16
#define NROWS 2048      // V*B per batch
#define DDIM 128

typedef __attribute__((ext_vector_type(8))) short bf16x8;
typedef __attribute__((ext_vector_type(4))) float f32x4;

// ---------------- Kernel 1: cast fp32 [16,1024,2,128] -> bf16 contrast [16,2048,128]
// contrast[b][v*1024 + i][d] = feat[b][i][v][d]
__global__ __launch_bounds__(256) void cast_reorder_kernel(
    const float* __restrict__ feat, __hip_bfloat16* __restrict__ out)
{
    int t = blockIdx.x * blockDim.x + threadIdx.x;     // 1,048,576 threads, 4 elems each
    int e = t << 2;
    int d = e & 127;
    int v = (e >> 7) & 1;
    int i = (e >> 8) & 1023;
    int b = e >> 18;
    const float4 f = *reinterpret_cast<const float4*>(feat + e);
    union { __hip_bfloat16 h[4]; uint2 u; } o;
    o.h[0] = __float2bfloat16(f.x);
    o.h[1] = __float2bfloat16(f.y);
    o.h[2] = __float2bfloat16(f.z);
    o.h[3] = __float2bfloat16(f.w);
    size_t oe = (size_t)(((b << 11) + (v << 10) + i)) * DDIM + d;
    *reinterpret_cast<uint2*>(out + oe) = o.u;
}

// ---------------- Kernel 2: fused Gram + online epilogue
// grid: 512 = 16 batches x 32 row-blocks(64 rows). block: 256 (4 waves, 2x2).
__global__ __launch_bounds__(256) void supcon_main_kernel(
    const __hip_bfloat16* __restrict__ contrast,   // [16][2048][128] bf16
    const int* __restrict__ labels,                // [16][1024]
    float* __restrict__ out)
{
    __shared__ __hip_bfloat16 At[64 * DDIM];     // 16 KB, XOR-swizzled
    __shared__ __hip_bfloat16 Bt[128 * DDIM];    // 32 KB, XOR-swizzled
    __shared__ int slab[1024];                   // 4 KB
    __shared__ float rsum[64], rpos[64], rcnt[64];

    const int tid  = threadIdx.x;
    const int lane = tid & 63;
    const int w    = tid >> 6;
    const int wrow = w >> 1;       // 0..1 : which 32-row half
    const int wcol = w & 1;        // 0..1 : which 64-col half
    const int bx = blockIdx.x;
    const int b  = bx >> 5;        // batch
    const int rb = bx & 31;        // row block
    const int n0 = rb * 64;

    const __hip_bfloat16* cb = contrast + (size_t)b * NROWS * DDIM;
    const int* lb = labels + b * 1024;

    // ---- stage A tile (rows n0..n0+63, contiguous 16KB), swizzled
    #pragma unroll
    for (int it = 0; it < 4; ++it) {
        int chunk = it * 256 + tid;           // 1024 x 16B chunks
        int row = chunk >> 4, c = chunk & 15;
        uint4 vdat = *reinterpret_cast<const uint4*>(cb + (size_t)(n0 + row) * DDIM + c * 8);
        *reinterpret_cast<uint4*>(At + row * DDIM + ((c ^ (row & 7)) << 3)) = vdat;
    }
    // ---- stage labels
    #pragma unroll
    for (int it = 0; it < 4; ++it) slab[it * 256 + tid] = lb[it * 256 + tid];
    if (tid < 64) { rsum[tid] = 0.f; rpos[tid] = 0.f; rcnt[tid] = 0.f; }
    __syncthreads();

    // ---- preload A fragments (constant across col tiles): 2 frag-rows x 4 k-steps
    bf16x8 afrag[2][4];
    #pragma unroll
    for (int fr = 0; fr < 2; ++fr) {
        int arow = wrow * 32 + fr * 16 + (lane & 15);
        #pragma unroll
        for (int ks = 0; ks < 4; ++ks) {
            int d = ks * 32 + ((lane >> 4) << 3);
            afrag[fr][ks] = *reinterpret_cast<const bf16x8*>(
                At + arow * DDIM + (d ^ ((arow & 7) << 3)));
        }
    }

    // ---- per-lane row ids/labels for the epilogue: row = n0+wrow*32+fr*16+(lane>>4)*4+j
    int rown[2][4], rowlab[2][4];
    #pragma unroll
    for (int fr = 0; fr < 2; ++fr)
        #pragma unroll
        for (int j = 0; j < 4; ++j) {
            int n = n0 + wrow * 32 + fr * 16 + ((lane >> 4) << 2) + j;
            rown[fr][j] = n;
            rowlab[fr][j] = slab[n & 1023];
        }

    float se[2][4] = {{0.f,0.f,0.f,0.f},{0.f,0.f,0.f,0.f}};   // sum exp(S-C), m != n
    float ps[2][4] = {{0.f,0.f,0.f,0.f},{0.f,0.f,0.f,0.f}};   // sum_pos dot
    float pc[2][4] = {{0.f,0.f,0.f,0.f},{0.f,0.f,0.f,0.f}};   // pos count

    for (int t = 0; t < 16; ++t) {
        const int m0 = t * 128;
        __syncthreads();   // previous iteration's MFMA reads of Bt are done
        #pragma unroll
        for (int it = 0; it < 8; ++it) {
            int chunk = it * 256 + tid;       // 2048 x 16B chunks
            int row = chunk >> 4, c = chunk & 15;
            uint4 vdat = *reinterpret_cast<const uint4*>(cb + (size_t)(m0 + row) * DDIM + c * 8);
            *reinterpret_cast<uint4*>(Bt + row * DDIM + ((c ^ (row & 7)) << 3)) = vdat;
        }
        __syncthreads();

        f32x4 acc[2][4];
        #pragma unroll
        for (int fr = 0; fr < 2; ++fr)
            #pragma unroll
            for (int fc = 0; fc < 4; ++fc)
                acc[fr][fc] = (f32x4){0.f, 0.f, 0.f, 0.f};

        #pragma unroll
        for (int ks = 0; ks < 4; ++ks) {
            bf16x8 bfrag[4];
            #pragma unroll
            for (int fc = 0; fc < 4; ++fc) {
                int brow = wcol * 64 + fc * 16 + (lane & 15);
                int d = ks * 32 + ((lane >> 4) << 3);
                bfrag[fc] = *reinterpret_cast<const bf16x8*>(
                    Bt + brow * DDIM + (d ^ ((brow & 7) << 3)));
            }
            #pragma unroll
            for (int fr = 0; fr < 2; ++fr)
                #pragma unroll
                for (int fc = 0; fc < 4; ++fc)
                    acc[fr][fc] = __builtin_amdgcn_mfma_f32_16x16x32_bf16(
                        afrag[fr][ks], bfrag[fc], acc[fr][fc], 0, 0, 0);
        }

        // ---- fused epilogue: exp-sum (excl diag), masked positive sum/count
        #pragma unroll
        for (int fc = 0; fc < 4; ++fc) {
            int m = m0 + wcol * 64 + fc * 16 + (lane & 15);
            int lm = slab[m & 1023];
            #pragma unroll
            for (int fr = 0; fr < 2; ++fr) {
                #pragma unroll
                for (int j = 0; j < 4; ++j) {
                    float val = acc[fr][fc][j];           // raw dot product
                    int n = rown[fr][j];
                    bool diag = (m == n);
                    float e = __expf(val * TEMP_INV - TEMP_INV);
                    if (diag) e = 0.f;
                    se[fr][j] += e;
                    bool p = (lm == rowlab[fr][j]) && !diag;
                    ps[fr][j] += p ? val : 0.f;
                    pc[fr][j] += p ? 1.f : 0.f;
                }
            }
        }
    }

    // ---- reduce the 16 column-lanes per row, combine the two wcol waves in LDS
    #pragma unroll
    for (int fr = 0; fr < 2; ++fr)
        #pragma unroll
        for (int j = 0; j < 4; ++j) {
            float s = se[fr][j], P = ps[fr][j], c = pc[fr][j];
            #pragma unroll
            for (int o = 1; o < 16; o <<= 1) {
                s += __shfl_xor(s, o);
                P += __shfl_xor(P, o);
                c += __shfl_xor(c, o);
            }
            if ((lane & 15) == 0) {
                int r = wrow * 32 + fr * 16 + ((lane >> 4) << 2) + j;
                atomicAdd(&rsum[r], s);
                atomicAdd(&rpos[r], P);
                atomicAdd(&rcnt[r], c);
            }
        }
    __syncthreads();

    if (tid < 64) {
        // row_loss = mean_log_prob_pos = possum*invT/cnt - C - log(sum exp(S-C))
        float row_loss = rpos[tid] * TEMP_INV / rcnt[tid] - TEMP_INV - __logf(rsum[tid]);
        float contrib = -row_loss * (1.0f / (float)(NBATCH * NROWS));
        #pragma unroll
        for (int o = 1; o < 64; o <<= 1) contrib += __shfl_xor(contrib, o);
        if (tid == 0) atomicAdd(out, contrib);
    }
}

extern "C" void kernel_launch(void* const* d_in, const int* in_sizes, int n_in,
                              void* d_out, int out_size, void* d_ws, size_t ws_size,
                              hipStream_t stream) {
    const float* feat  = (const float*)d_in[0];
    const int* labels  = (const int*)d_in[1];
    float* out = (float*)d_out;
    __hip_bfloat16* contrast = (__hip_bfloat16*)d_ws;   // 16*2048*128*2B = 8.4 MB

    hipMemsetAsync(d_out, 0, sizeof(float), stream);
    cast_reorder_kernel<<<4096, 256, 0, stream>>>(feat, contrast);
    supcon_main_kernel<<<512, 256, 0, stream>>>(contrast, labels, out);
}